// Round 5
// baseline (2766.986 us; speedup 1.0000x reference)
//
#include <hip/hip_runtime.h>
#include <cstdint>
#include <cstddef>

typedef unsigned long long u64;

#define NB 16
#define NC 64
#define NN 4096
#define NM 1024
#define NK 32

// ---------- DPP wave-reduction helpers (row_shr 1/2/4/8 + row_bcast 15/31) ----------

template <int C>
__device__ __forceinline__ float dppf(float x, float ident) {
  return __int_as_float(__builtin_amdgcn_update_dpp(
      __float_as_int(ident), __float_as_int(x), C, 0xf, 0xf, false));
}

template <int C>
__device__ __forceinline__ unsigned dppu(unsigned x, unsigned ident) {
  return (unsigned)__builtin_amdgcn_update_dpp(
      (int)ident, (int)x, C, 0xf, 0xf, false);
}

__device__ __forceinline__ float wave_fmin(float x) {
  const float I = __int_as_float(0x7f800000);  // +inf
  x = fminf(x, dppf<0x111>(x, I));
  x = fminf(x, dppf<0x112>(x, I));
  x = fminf(x, dppf<0x114>(x, I));
  x = fminf(x, dppf<0x118>(x, I));
  x = fminf(x, dppf<0x142>(x, I));
  x = fminf(x, dppf<0x143>(x, I));
  return __int_as_float(__builtin_amdgcn_readlane(__float_as_int(x), 63));
}

__device__ __forceinline__ unsigned wave_umin(unsigned x) {
  const unsigned I = 0xFFFFFFFFu;
  unsigned t;
  t = dppu<0x111>(x, I); x = x < t ? x : t;
  t = dppu<0x112>(x, I); x = x < t ? x : t;
  t = dppu<0x114>(x, I); x = x < t ? x : t;
  t = dppu<0x118>(x, I); x = x < t ? x : t;
  t = dppu<0x142>(x, I); x = x < t ? x : t;
  t = dppu<0x143>(x, I); x = x < t ? x : t;
  return (unsigned)__builtin_amdgcn_readlane((int)x, 63);
}

// ---------- kernel 0: pad W1 (64x67) -> W1p (64x68, zero col 67) ----------

__global__ __launch_bounds__(256) void pad_w1(const float* __restrict__ W1,
                                              float* __restrict__ W1p) {
  int g = blockIdx.x * 256 + threadIdx.x;
  if (g >= 64 * 68) return;
  int o = g / 68, c = g - o * 68;
  W1p[g] = (c < 67) ? W1[o * 67 + c] : 0.0f;
}

// ---------- kernel 1: feat (b,c,n) -> featT (b,n,c) ----------

__global__ __launch_bounds__(256) void transpose_feat(const float* __restrict__ feat,
                                                      float* __restrict__ featT) {
  int g = blockIdx.x * 256 + threadIdx.x;     // < NB*NN*NC
  int c = g & 63;
  int n = (g >> 6) & 4095;
  int b = g >> 18;
  featT[g] = feat[((size_t)(b * NC + c)) * NN + n];
}

// ---------- kernel 2: farthest point sampling ----------
// 256 threads (4 waves, 1/SIMD), 16 CONTIGUOUS points per thread, coords in
// registers. In-thread TREE argmax (first-index on ties), then value+coords
// ride a 6-stage DPP reduction (incoming = lower lanes, >= keeps first-max)
// so lane 63 holds the wave winner -- NO ballot/ffs/readlane SALU round-trips.
// One barrier/step; winners captured in a register shift queue, bulk-stored.

__global__ __launch_bounds__(256) void fps_kernel(const float* __restrict__ loc,
                                                  float* __restrict__ out_setloc) {
  __shared__ float4 red[2][4];
  const int b = blockIdx.x;
  const int tid = threadIdx.x;
  const int lane = tid & 63, wid = tid >> 6;
  const float* Lx = loc + (size_t)b * 3 * NN;
  const float* Ly = Lx + NN;
  const float* Lz = Ly + NN;
  const int p0 = tid * 16;
  float px[16], py[16], pz[16], dist[16];
#pragma unroll
  for (int j4 = 0; j4 < 4; ++j4) {
    float4 vx = *(const float4*)(Lx + p0 + 4 * j4);
    float4 vy = *(const float4*)(Ly + p0 + 4 * j4);
    float4 vz = *(const float4*)(Lz + p0 + 4 * j4);
    px[4 * j4] = vx.x; px[4 * j4 + 1] = vx.y; px[4 * j4 + 2] = vx.z; px[4 * j4 + 3] = vx.w;
    py[4 * j4] = vy.x; py[4 * j4 + 1] = vy.y; py[4 * j4 + 2] = vy.z; py[4 * j4 + 3] = vy.w;
    pz[4 * j4] = vz.x; pz[4 * j4 + 1] = vz.y; pz[4 * j4 + 2] = vz.z; pz[4 * j4 + 3] = vz.w;
  }
#pragma unroll
  for (int j = 0; j < 16; ++j) dist[j] = __int_as_float(0x7f800000);
  if (tid == 0) red[1][0] = make_float4(0.0f, px[0], py[0], pz[0]);  // bootstrap: point 0
  __syncthreads();
  float4 boot = red[1][0];
  float sx = boot.y, sy = boot.z, sz = boot.w;

  // register shift-queue of captured winners (slot s captured by tid == s%256)
  float w0x = 0, w0y = 0, w0z = 0, w1x = 0, w1y = 0, w1z = 0;
  float w2x = 0, w2y = 0, w2z = 0, w3x = 0, w3y = 0, w3z = 0;
  if (tid == 0) { w0x = sx; w0y = sy; w0z = sz; }  // slot 0 = point 0

  const float NEGINF = __int_as_float(0xff800000);

  for (int s = 0; s < NM - 1; ++s) {  // compute winners for slots 1..1023
    // distance update (exact numpy arithmetic), new dist values in v[]
    float v[16];
#pragma unroll
    for (int j = 0; j < 16; ++j) {
      float dx = __fsub_rn(px[j], sx);
      float dy = __fsub_rn(py[j], sy);
      float dz = __fsub_rn(pz[j], sz);
      float d2 = __fadd_rn(__fadd_rn(__fmul_rn(dx, dx), __fmul_rn(dy, dy)), __fmul_rn(dz, dz));
      float nd = fminf(dist[j], d2);
      dist[j] = nd;
      v[j] = nd;
    }
    // in-thread tree argmax (prefer LEFT on ties == first index), depth 4
    float t8v[8], t8x[8], t8y[8], t8z[8];
#pragma unroll
    for (int j = 0; j < 8; ++j) {
      bool g = v[2 * j + 1] > v[2 * j];
      t8v[j] = g ? v[2 * j + 1] : v[2 * j];
      t8x[j] = g ? px[2 * j + 1] : px[2 * j];
      t8y[j] = g ? py[2 * j + 1] : py[2 * j];
      t8z[j] = g ? pz[2 * j + 1] : pz[2 * j];
    }
    float t4v[4], t4x[4], t4y[4], t4z[4];
#pragma unroll
    for (int j = 0; j < 4; ++j) {
      bool g = t8v[2 * j + 1] > t8v[2 * j];
      t4v[j] = g ? t8v[2 * j + 1] : t8v[2 * j];
      t4x[j] = g ? t8x[2 * j + 1] : t8x[2 * j];
      t4y[j] = g ? t8y[2 * j + 1] : t8y[2 * j];
      t4z[j] = g ? t8z[2 * j + 1] : t8z[2 * j];
    }
    float t2v[2], t2x[2], t2y[2], t2z[2];
#pragma unroll
    for (int j = 0; j < 2; ++j) {
      bool g = t4v[2 * j + 1] > t4v[2 * j];
      t2v[j] = g ? t4v[2 * j + 1] : t4v[2 * j];
      t2x[j] = g ? t4x[2 * j + 1] : t4x[2 * j];
      t2y[j] = g ? t4y[2 * j + 1] : t4y[2 * j];
      t2z[j] = g ? t4z[2 * j + 1] : t4z[2 * j];
    }
    bool gg = t2v[1] > t2v[0];
    float bv = gg ? t2v[1] : t2v[0];
    float bx = gg ? t2x[1] : t2x[0];
    float by = gg ? t2y[1] : t2y[0];
    float bz = gg ? t2z[1] : t2z[0];

    // 6-stage DPP wave reduce, payload rides along; incoming (lower lanes)
    // wins ties via >= -> first-max; lane 63 ends with the wave winner.
#define FPS_MERGE(CTRL) { \
      float iv = dppf<CTRL>(bv, NEGINF); \
      float ix = dppf<CTRL>(bx, 0.0f); \
      float iy = dppf<CTRL>(by, 0.0f); \
      float iz = dppf<CTRL>(bz, 0.0f); \
      bool tk = iv >= bv; \
      bv = tk ? iv : bv; bx = tk ? ix : bx; by = tk ? iy : by; bz = tk ? iz : bz; }
    FPS_MERGE(0x111) FPS_MERGE(0x112) FPS_MERGE(0x114) FPS_MERGE(0x118)
    FPS_MERGE(0x142) FPS_MERGE(0x143)
#undef FPS_MERGE

    if (lane == 63) red[s & 1][wid] = make_float4(bv, bx, by, bz);
    __syncthreads();
    // stage 2: 4 candidates, prefer lower wid on ties (== lower index)
    float4 c0 = red[s & 1][0], c1 = red[s & 1][1], c2 = red[s & 1][2], c3 = red[s & 1][3];
    bool h0 = c1.x > c0.x;
    float m0v = h0 ? c1.x : c0.x, m0x = h0 ? c1.y : c0.y, m0y = h0 ? c1.z : c0.z, m0z = h0 ? c1.w : c0.w;
    bool h1 = c3.x > c2.x;
    float m1v = h1 ? c3.x : c2.x, m1x = h1 ? c3.y : c2.y, m1y = h1 ? c3.z : c2.z, m1z = h1 ? c3.w : c2.w;
    bool h2 = m1v > m0v;
    sx = h2 ? m1x : m0x; sy = h2 ? m1y : m0y; sz = h2 ? m1z : m0z;

    // capture slot s+1 into the shift queue (static indices only)
    if (tid == ((s + 1) & 255)) {
      w3x = w2x; w3y = w2y; w3z = w2z;
      w2x = w1x; w2y = w1y; w2z = w1z;
      w1x = w0x; w1y = w0y; w1z = w0z;
      w0x = sx;  w0y = sy;  w0z = sz;
    }
  }
  // thread t holds slots t(w3), t+256(w2), t+512(w1), t+768(w0); coalesced write
  float* Ox = out_setloc + (b * 3 + 0) * NM;
  float* Oy = out_setloc + (b * 3 + 1) * NM;
  float* Oz = out_setloc + (b * 3 + 2) * NM;
  Ox[tid] = w3x;       Oy[tid] = w3y;       Oz[tid] = w3z;
  Ox[tid + 256] = w2x; Oy[tid + 256] = w2y; Oz[tid + 256] = w2z;
  Ox[tid + 512] = w1x; Oy[tid + 512] = w1y; Oz[tid + 512] = w1z;
  Ox[tid + 768] = w0x; Oy[tid + 768] = w0y; Oz[tid + 768] = w0z;
}

// ---------- kernel 3: kNN (one wave per query, DPP-min extraction) ----------

__global__ __launch_bounds__(256) void knn_kernel(const float* __restrict__ loc,
                                                  const float* __restrict__ setloc,
                                                  int* __restrict__ ws_knn) {
  const int wq = blockIdx.x * 4 + (threadIdx.x >> 6);  // query id, < NB*NM
  const int lane = threadIdx.x & 63;
  const int b = wq >> 10, mq = wq & 1023;
  const float* Sb = setloc + (size_t)b * 3 * NM;
  float xs = Sb[mq], ys = Sb[NM + mq], zs = Sb[2 * NM + mq];
  float sqs = __fadd_rn(__fadd_rn(__fmul_rn(xs, xs), __fmul_rn(ys, ys)), __fmul_rn(zs, zs));
  const float* Lx = loc + (size_t)b * 3 * NN;
  const float* Ly = Lx + NN;
  const float* Lz = Ly + NN;
  const float INF = __int_as_float(0x7f800000);

  // per-lane two smallest (value, index); lane owns points p = j*64+lane
  float k1 = INF, k2 = INF;
  unsigned i1 = 0xFFFFFFFFu, i2 = 0xFFFFFFFFu;
#pragma unroll 8
  for (int j = 0; j < 64; ++j) {
    int p = j * 64 + lane;
    float x = Lx[p], y = Ly[p], z = Lz[p];
    float sql = __fadd_rn(__fadd_rn(__fmul_rn(x, x), __fmul_rn(y, y)), __fmul_rn(z, z));
    float cr  = __fadd_rn(__fadd_rn(__fmul_rn(xs, x), __fmul_rn(ys, y)), __fmul_rn(zs, z));
    float d2  = __fsub_rn(__fadd_rn(sqs, sql), __fmul_rn(2.0f, cr));
    if (d2 < k1)      { k2 = k1; i2 = i1; k1 = d2; i1 = (unsigned)p; }
    else if (d2 < k2) { k2 = d2; i2 = (unsigned)p; }
  }

  u64 used = 0;        // per-lane mask of extracted j-slots
  unsigned keep = 0;   // lane s holds round-s winner
  for (int s = 0; s < NK; ++s) {
    float wmin = wave_fmin(k1);
    u64 mask = __ballot(k1 == wmin);
    int ownerLane;
    if (__popcll(mask) > 1) {
      // exact tie-break: smallest global index among tied lanes
      unsigned cand = (k1 == wmin) ? i1 : 0xFFFFFFFFu;
      unsigned minp = wave_umin(cand);
      u64 m2 = __ballot(k1 == wmin && i1 == minp);
      ownerLane = __ffsll((long long)m2) - 1;
    } else {
      ownerLane = __ffsll((long long)mask) - 1;
    }
    unsigned widx = (unsigned)__builtin_amdgcn_readlane((int)i1, ownerLane);
    if (lane == s) keep = widx;
    if (lane == ownerLane) {
      used |= 1ull << (i1 >> 6);
      k1 = k2; i1 = i2;
      k2 = INF; i2 = 0xFFFFFFFFu;
      if (__float_as_uint(k1) == 0x7f800000u) {
        // rare refill: recompute this lane's remaining distances (L2-hot loc)
#pragma unroll 8
        for (int j = 0; j < 64; ++j) {
          if (!((used >> j) & 1ull)) {
            int p = j * 64 + lane;
            float x = Lx[p], y = Ly[p], z = Lz[p];
            float sql = __fadd_rn(__fadd_rn(__fmul_rn(x, x), __fmul_rn(y, y)), __fmul_rn(z, z));
            float cr  = __fadd_rn(__fadd_rn(__fmul_rn(xs, x), __fmul_rn(ys, y)), __fmul_rn(zs, z));
            float d2  = __fsub_rn(__fadd_rn(sqs, sql), __fmul_rn(2.0f, cr));
            if (d2 < k1)      { k2 = k1; i2 = i1; k1 = d2; i1 = (unsigned)p; }
            else if (d2 < k2) { k2 = d2; i2 = (unsigned)p; }
          }
        }
      }
    }
  }
  if (lane < NK) ws_knn[(size_t)wq * NK + lane] = (int)keep;
}

// ---------- kernel 4: fused gather + 3-layer MLP + maxpool ----------

#define RELU8() { a0=fmaxf(a0,0.f); a1=fmaxf(a1,0.f); a2=fmaxf(a2,0.f); a3=fmaxf(a3,0.f); \
                  a4=fmaxf(a4,0.f); a5=fmaxf(a5,0.f); a6=fmaxf(a6,0.f); a7=fmaxf(a7,0.f); }
#define SCROW(Y, base) { Y[base]=a0; Y[base+1]=a1; Y[base+2]=a2; Y[base+3]=a3; \
                         Y[base+4]=a4; Y[base+5]=a5; Y[base+6]=a6; Y[base+7]=a7; }
#define SCAT8(Y) switch (ob) { \
    case 0: SCROW(Y, 0) break;  case 1: SCROW(Y, 8) break; \
    case 2: SCROW(Y, 16) break; case 3: SCROW(Y, 24) break; \
    case 4: SCROW(Y, 32) break; case 5: SCROW(Y, 40) break; \
    case 6: SCROW(Y, 48) break; case 7: SCROW(Y, 56) break; }
#define BFLY(a) { a = fmaxf(a, __shfl_xor(a, 16, 64)); a = fmaxf(a, __shfl_xor(a, 8, 64)); \
                  a = fmaxf(a, __shfl_xor(a, 4, 64));  a = fmaxf(a, __shfl_xor(a, 2, 64)); \
                  a = fmaxf(a, __shfl_xor(a, 1, 64)); }

// one 4-c chunk of row R accumulated into ACC (explicit float4 weight load)
#define ROW4(ACC, R, STRIDE) { \
    float4 w = *(const float4*)(wr + (R) * (STRIDE) + 4 * ch); \
    ACC = fmaf(w.x, x0, ACC); ACC = fmaf(w.y, x1, ACC); \
    ACC = fmaf(w.z, x2, ACC); ACC = fmaf(w.w, x3, ACC); }

#define CHUNK8(XS, STRIDE) { \
    float x0 = XS[4 * ch], x1 = XS[4 * ch + 1], x2 = XS[4 * ch + 2], x3 = XS[4 * ch + 3]; \
    ROW4(a0, 0, STRIDE) ROW4(a1, 1, STRIDE) ROW4(a2, 2, STRIDE) ROW4(a3, 3, STRIDE) \
    ROW4(a4, 4, STRIDE) ROW4(a5, 5, STRIDE) ROW4(a6, 6, STRIDE) ROW4(a7, 7, STRIDE) }

__global__ __launch_bounds__(256) void mlp_kernel(
    const float* __restrict__ featT, const float* __restrict__ loc,
    const float* __restrict__ setloc, const int* __restrict__ ws_knn,
    const float* __restrict__ W1p, const float* __restrict__ b1,
    const float* __restrict__ W2, const float* __restrict__ b2,
    const float* __restrict__ W3, const float* __restrict__ b3,
    float* __restrict__ out) {
  const int lane = threadIdx.x & 63;
  const int wix = blockIdx.x * 4 + (threadIdx.x >> 6);  // wave id, < 8192
  const int q = wix * 2 + (lane >> 5);                  // query id, < 16384
  const int col = lane & 31;                            // neighbor slot (k)
  const int b = q >> 10, mq = q & 1023;
  const int nk = ws_knn[(size_t)q * NK + col];

  // gather input column: 64 feat channels + 3 rel-loc + zero pad
  const float* fx = featT + ((size_t)(b * NN + nk)) * 64;
  float x[68];
#pragma unroll
  for (int i = 0; i < 16; ++i) {
    float4 v = *(const float4*)(fx + 4 * i);
    x[4 * i] = v.x; x[4 * i + 1] = v.y; x[4 * i + 2] = v.z; x[4 * i + 3] = v.w;
  }
  {
    const float* Lb = loc + (size_t)b * 3 * NN;
    const float* Sb = setloc + (size_t)b * 3 * NM;
    x[64] = Lb[nk] - Sb[mq];
    x[65] = Lb[NN + nk] - Sb[NM + mq];
    x[66] = Lb[2 * NN + nk] - Sb[2 * NM + mq];
    x[67] = 0.0f;  // pairs with W1p zero column
  }

  // layer 1: 68 -> 64 (padded)
  float y1[64];
#pragma unroll 1
  for (int ob = 0; ob < 8; ++ob) {
    const float* wr = W1p + (size_t)ob * 8 * 68;
    const float* bb = b1 + ob * 8;
    float a0 = bb[0], a1 = bb[1], a2 = bb[2], a3 = bb[3];
    float a4 = bb[4], a5 = bb[5], a6 = bb[6], a7 = bb[7];
#pragma unroll
    for (int ch = 0; ch < 17; ++ch) CHUNK8(x, 68)
    RELU8();
    SCAT8(y1);
  }

  // layer 2: 64 -> 64
  float y2[64];
#pragma unroll 1
  for (int ob = 0; ob < 8; ++ob) {
    const float* wr = W2 + (size_t)ob * 8 * 64;
    const float* bb = b2 + ob * 8;
    float a0 = bb[0], a1 = bb[1], a2 = bb[2], a3 = bb[3];
    float a4 = bb[4], a5 = bb[5], a6 = bb[6], a7 = bb[7];
#pragma unroll
    for (int ch = 0; ch < 16; ++ch) CHUNK8(y1, 64)
    RELU8();
    SCAT8(y2);
  }

  // layer 3: 64 -> 128, fused maxpool over the 32 columns + store
#pragma unroll 1
  for (int ob = 0; ob < 16; ++ob) {
    const float* wr = W3 + (size_t)ob * 8 * 64;
    const float* bb = b3 + ob * 8;
    float a0 = bb[0], a1 = bb[1], a2 = bb[2], a3 = bb[3];
    float a4 = bb[4], a5 = bb[5], a6 = bb[6], a7 = bb[7];
#pragma unroll
    for (int ch = 0; ch < 16; ++ch) CHUNK8(y2, 64)
    RELU8();
    BFLY(a0); BFLY(a1); BFLY(a2); BFLY(a3);
    BFLY(a4); BFLY(a5); BFLY(a6); BFLY(a7);
    if (col == 0) {
      float* op = out + ((size_t)b * 128 + ob * 8) * NM + mq;
      op[0] = a0;       op[NM] = a1;     op[2 * NM] = a2; op[3 * NM] = a3;
      op[4 * NM] = a4;  op[5 * NM] = a5; op[6 * NM] = a6; op[7 * NM] = a7;
    }
  }
}

// ---------- launch ----------

extern "C" void kernel_launch(void* const* d_in, const int* in_sizes, int n_in,
                              void* d_out, int out_size, void* d_ws, size_t ws_size,
                              hipStream_t stream) {
  (void)in_sizes; (void)n_in; (void)out_size; (void)ws_size;
  const float* feat = (const float*)d_in[0];
  const float* loc  = (const float*)d_in[1];
  const float* W1   = (const float*)d_in[2];
  const float* b1   = (const float*)d_in[3];
  const float* W2   = (const float*)d_in[4];
  const float* b2   = (const float*)d_in[5];
  const float* W3   = (const float*)d_in[6];
  const float* b3   = (const float*)d_in[7];
  float* out = (float*)d_out;

  char* ws = (char*)d_ws;
  int*   ws_knn   = (int*)ws;                           // 16*1024*32 i32 = 2 MB
  float* ws_featT = (float*)(ws + 2097152);             // 16*4096*64 f32 = 16.75 MB
  float* ws_w1p   = (float*)(ws + 2097152 + 16777216);  // 64*68 f32

  float* out_setfeat = out;                          // (16,128,1024)
  float* out_setloc  = out + (size_t)NB * 128 * NM;  // (16,3,1024)

  pad_w1<<<dim3(17), dim3(256), 0, stream>>>(W1, ws_w1p);
  transpose_feat<<<dim3((NB * NN * NC) / 256), dim3(256), 0, stream>>>(feat, ws_featT);
  fps_kernel<<<dim3(NB), dim3(256), 0, stream>>>(loc, out_setloc);
  knn_kernel<<<dim3((NB * NM) / 4), dim3(256), 0, stream>>>(loc, out_setloc, ws_knn);
  mlp_kernel<<<dim3((NB * NM) / 8), dim3(256), 0, stream>>>(
      ws_featT, loc, out_setloc, ws_knn, ws_w1p, b1, W2, b2, W3, b3, out_setfeat);
}

// Round 6
// 1552.468 us; speedup vs baseline: 1.7823x; 1.7823x over previous
//
#include <hip/hip_runtime.h>
#include <cstdint>
#include <cstddef>

typedef unsigned long long u64;

#define NB 16
#define NC 64
#define NN 4096
#define NM 1024
#define NK 32

// ---------- DPP wave-reduction helpers (row_shr 1/2/4/8 + row_bcast 15/31) ----------

template <int C>
__device__ __forceinline__ float dppf(float x, float ident) {
  return __int_as_float(__builtin_amdgcn_update_dpp(
      __float_as_int(ident), __float_as_int(x), C, 0xf, 0xf, false));
}

template <int C>
__device__ __forceinline__ unsigned dppu(unsigned x, unsigned ident) {
  return (unsigned)__builtin_amdgcn_update_dpp(
      (int)ident, (int)x, C, 0xf, 0xf, false);
}

// full-wave (64-lane) float max; result broadcast via readlane(63)
__device__ __forceinline__ float wave_fmax(float x) {
  const float I = __int_as_float(0xff800000);  // -inf
  x = fmaxf(x, dppf<0x111>(x, I));
  x = fmaxf(x, dppf<0x112>(x, I));
  x = fmaxf(x, dppf<0x114>(x, I));
  x = fmaxf(x, dppf<0x118>(x, I));
  x = fmaxf(x, dppf<0x142>(x, I));  // row_bcast:15
  x = fmaxf(x, dppf<0x143>(x, I));  // row_bcast:31
  return __int_as_float(__builtin_amdgcn_readlane(__float_as_int(x), 63));
}

__device__ __forceinline__ float wave_fmin(float x) {
  const float I = __int_as_float(0x7f800000);  // +inf
  x = fminf(x, dppf<0x111>(x, I));
  x = fminf(x, dppf<0x112>(x, I));
  x = fminf(x, dppf<0x114>(x, I));
  x = fminf(x, dppf<0x118>(x, I));
  x = fminf(x, dppf<0x142>(x, I));
  x = fminf(x, dppf<0x143>(x, I));
  return __int_as_float(__builtin_amdgcn_readlane(__float_as_int(x), 63));
}

__device__ __forceinline__ unsigned wave_umin(unsigned x) {
  const unsigned I = 0xFFFFFFFFu;
  unsigned t;
  t = dppu<0x111>(x, I); x = x < t ? x : t;
  t = dppu<0x112>(x, I); x = x < t ? x : t;
  t = dppu<0x114>(x, I); x = x < t ? x : t;
  t = dppu<0x118>(x, I); x = x < t ? x : t;
  t = dppu<0x142>(x, I); x = x < t ? x : t;
  t = dppu<0x143>(x, I); x = x < t ? x : t;
  return (unsigned)__builtin_amdgcn_readlane((int)x, 63);
}

// ---------- kernel 0: pad W1 (64x67) -> W1p (64x68, zero col 67) ----------

__global__ __launch_bounds__(256) void pad_w1(const float* __restrict__ W1,
                                              float* __restrict__ W1p) {
  int g = blockIdx.x * 256 + threadIdx.x;
  if (g >= 64 * 68) return;
  int o = g / 68, c = g - o * 68;
  W1p[g] = (c < 67) ? W1[o * 67 + c] : 0.0f;
}

// ---------- kernel 1: feat (b,c,n) -> featT (b,n,c) ----------

__global__ __launch_bounds__(256) void transpose_feat(const float* __restrict__ feat,
                                                      float* __restrict__ featT) {
  int g = blockIdx.x * 256 + threadIdx.x;     // < NB*NN*NC
  int c = g & 63;
  int n = (g >> 6) & 4095;
  int b = g >> 18;
  featT[g] = feat[((size_t)(b * NC + c)) * NN + n];
}

// ---------- kernel 2: farthest point sampling (R4 version, verbatim) ----------
// 256 threads (4 waves, 1/SIMD), 16 CONTIGUOUS points per thread, coords in
// registers; winner coords travel through the reduction. NO global stores in
// the loop (winners captured in a 4-deep register shift queue per thread,
// one coalesced write at the end) -> barrier never waits on vmcnt drain.
// NOTE (R5 lesson): serial scan + wave_fmax/ballot BEATS tree-argmax +
// payload-riding DPP (SGPR pressure + DPP hazards made that 2.4x slower).

__global__ __launch_bounds__(256) void fps_kernel(const float* __restrict__ loc,
                                                  float* __restrict__ out_setloc) {
  __shared__ float4 red[2][4];
  const int b = blockIdx.x;
  const int tid = threadIdx.x;
  const int lane = tid & 63, wid = tid >> 6;
  const float* Lx = loc + (size_t)b * 3 * NN;
  const float* Ly = Lx + NN;
  const float* Lz = Ly + NN;
  const int p0 = tid * 16;
  float px[16], py[16], pz[16], dist[16];
#pragma unroll
  for (int j4 = 0; j4 < 4; ++j4) {
    float4 vx = *(const float4*)(Lx + p0 + 4 * j4);
    float4 vy = *(const float4*)(Ly + p0 + 4 * j4);
    float4 vz = *(const float4*)(Lz + p0 + 4 * j4);
    px[4 * j4] = vx.x; px[4 * j4 + 1] = vx.y; px[4 * j4 + 2] = vx.z; px[4 * j4 + 3] = vx.w;
    py[4 * j4] = vy.x; py[4 * j4 + 1] = vy.y; py[4 * j4 + 2] = vy.z; py[4 * j4 + 3] = vy.w;
    pz[4 * j4] = vz.x; pz[4 * j4 + 1] = vz.y; pz[4 * j4 + 2] = vz.z; pz[4 * j4 + 3] = vz.w;
  }
#pragma unroll
  for (int j = 0; j < 16; ++j) dist[j] = __int_as_float(0x7f800000);
  if (tid == 0) red[1][0] = make_float4(0.0f, px[0], py[0], pz[0]);  // bootstrap: point 0
  __syncthreads();
  float4 boot = red[1][0];
  float sx = boot.y, sy = boot.z, sz = boot.w;

  // register shift-queue of captured winners (slot s captured by tid == s%256)
  float w0x = 0, w0y = 0, w0z = 0, w1x = 0, w1y = 0, w1z = 0;
  float w2x = 0, w2y = 0, w2z = 0, w3x = 0, w3y = 0, w3z = 0;
  if (tid == 0) { w0x = sx; w0y = sy; w0z = sz; }  // slot 0 = point 0

  for (int s = 0; s < NM - 1; ++s) {  // compute winners for slots 1..1023
    float bd = -1.0f, bx = 0.0f, by = 0.0f, bz = 0.0f;
#pragma unroll
    for (int j = 0; j < 16; ++j) {
      // match numpy: plain mul, left-assoc adds, no contraction
      float dx = __fsub_rn(px[j], sx);
      float dy = __fsub_rn(py[j], sy);
      float dz = __fsub_rn(pz[j], sz);
      float d2 = __fadd_rn(__fadd_rn(__fmul_rn(dx, dx), __fmul_rn(dy, dy)), __fmul_rn(dz, dz));
      float nd = fminf(dist[j], d2);
      dist[j] = nd;
      bool g = nd > bd;  // strict > keeps lowest j (= lowest index)
      bd = g ? nd : bd;
      bx = g ? px[j] : bx;
      by = g ? py[j] : by;
      bz = g ? pz[j] : bz;
    }
    // wave argmax: DPP value max, lowest tied lane (= lowest index) writes cand
    float wmax = wave_fmax(bd);
    u64 m = __ballot(bd == wmax);
    if (lane == __ffsll((long long)m) - 1) red[s & 1][wid] = make_float4(bd, bx, by, bz);
    __syncthreads();
    // 4-way serial argmax, ascending wid + strict > == global first-max
    float4 c0 = red[s & 1][0], c1 = red[s & 1][1], c2 = red[s & 1][2], c3 = red[s & 1][3];
    float bdd = c0.x; sx = c0.y; sy = c0.z; sz = c0.w;
    bool g1 = c1.x > bdd; bdd = g1 ? c1.x : bdd; sx = g1 ? c1.y : sx; sy = g1 ? c1.z : sy; sz = g1 ? c1.w : sz;
    bool g2 = c2.x > bdd; bdd = g2 ? c2.x : bdd; sx = g2 ? c2.y : sx; sy = g2 ? c2.z : sy; sz = g2 ? c2.w : sz;
    bool g3 = c3.x > bdd; bdd = g3 ? c3.x : bdd; sx = g3 ? c3.y : sx; sy = g3 ? c3.z : sy; sz = g3 ? c3.w : sz;
    // capture slot s+1 into the shift queue (static indices only)
    if (tid == ((s + 1) & 255)) {
      w3x = w2x; w3y = w2y; w3z = w2z;
      w2x = w1x; w2y = w1y; w2z = w1z;
      w1x = w0x; w1y = w0y; w1z = w0z;
      w0x = sx;  w0y = sy;  w0z = sz;
    }
  }
  // thread t holds slots t(w3), t+256(w2), t+512(w1), t+768(w0); coalesced write
  float* Ox = out_setloc + (b * 3 + 0) * NM;
  float* Oy = out_setloc + (b * 3 + 1) * NM;
  float* Oz = out_setloc + (b * 3 + 2) * NM;
  Ox[tid] = w3x;       Oy[tid] = w3y;       Oz[tid] = w3z;
  Ox[tid + 256] = w2x; Oy[tid + 256] = w2y; Oz[tid + 256] = w2z;
  Ox[tid + 512] = w1x; Oy[tid + 512] = w1y; Oz[tid + 512] = w1z;
  Ox[tid + 768] = w0x; Oy[tid + 768] = w0y; Oz[tid + 768] = w0z;
}

// ---------- kernel 3: kNN (one wave per query, DPP-min extraction) ----------

__global__ __launch_bounds__(256) void knn_kernel(const float* __restrict__ loc,
                                                  const float* __restrict__ setloc,
                                                  int* __restrict__ ws_knn) {
  const int wq = blockIdx.x * 4 + (threadIdx.x >> 6);  // query id, < NB*NM
  const int lane = threadIdx.x & 63;
  const int b = wq >> 10, mq = wq & 1023;
  const float* Sb = setloc + (size_t)b * 3 * NM;
  float xs = Sb[mq], ys = Sb[NM + mq], zs = Sb[2 * NM + mq];
  float sqs = __fadd_rn(__fadd_rn(__fmul_rn(xs, xs), __fmul_rn(ys, ys)), __fmul_rn(zs, zs));
  const float* Lx = loc + (size_t)b * 3 * NN;
  const float* Ly = Lx + NN;
  const float* Lz = Ly + NN;
  const float INF = __int_as_float(0x7f800000);

  // per-lane two smallest (value, index); lane owns points p = j*64+lane
  float k1 = INF, k2 = INF;
  unsigned i1 = 0xFFFFFFFFu, i2 = 0xFFFFFFFFu;
#pragma unroll 8
  for (int j = 0; j < 64; ++j) {
    int p = j * 64 + lane;
    float x = Lx[p], y = Ly[p], z = Lz[p];
    float sql = __fadd_rn(__fadd_rn(__fmul_rn(x, x), __fmul_rn(y, y)), __fmul_rn(z, z));
    float cr  = __fadd_rn(__fadd_rn(__fmul_rn(xs, x), __fmul_rn(ys, y)), __fmul_rn(zs, z));
    float d2  = __fsub_rn(__fadd_rn(sqs, sql), __fmul_rn(2.0f, cr));
    if (d2 < k1)      { k2 = k1; i2 = i1; k1 = d2; i1 = (unsigned)p; }
    else if (d2 < k2) { k2 = d2; i2 = (unsigned)p; }
  }

  u64 used = 0;        // per-lane mask of extracted j-slots
  unsigned keep = 0;   // lane s holds round-s winner
  for (int s = 0; s < NK; ++s) {
    float wmin = wave_fmin(k1);
    u64 mask = __ballot(k1 == wmin);
    int ownerLane;
    if (__popcll(mask) > 1) {
      // exact tie-break: smallest global index among tied lanes
      unsigned cand = (k1 == wmin) ? i1 : 0xFFFFFFFFu;
      unsigned minp = wave_umin(cand);
      u64 m2 = __ballot(k1 == wmin && i1 == minp);
      ownerLane = __ffsll((long long)m2) - 1;
    } else {
      ownerLane = __ffsll((long long)mask) - 1;
    }
    unsigned widx = (unsigned)__builtin_amdgcn_readlane((int)i1, ownerLane);
    if (lane == s) keep = widx;
    if (lane == ownerLane) {
      used |= 1ull << (i1 >> 6);
      k1 = k2; i1 = i2;
      k2 = INF; i2 = 0xFFFFFFFFu;
      if (__float_as_uint(k1) == 0x7f800000u) {
        // rare refill: recompute this lane's remaining distances (L2-hot loc)
#pragma unroll 8
        for (int j = 0; j < 64; ++j) {
          if (!((used >> j) & 1ull)) {
            int p = j * 64 + lane;
            float x = Lx[p], y = Ly[p], z = Lz[p];
            float sql = __fadd_rn(__fadd_rn(__fmul_rn(x, x), __fmul_rn(y, y)), __fmul_rn(z, z));
            float cr  = __fadd_rn(__fadd_rn(__fmul_rn(xs, x), __fmul_rn(ys, y)), __fmul_rn(zs, z));
            float d2  = __fsub_rn(__fadd_rn(sqs, sql), __fmul_rn(2.0f, cr));
            if (d2 < k1)      { k2 = k1; i2 = i1; k1 = d2; i1 = (unsigned)p; }
            else if (d2 < k2) { k2 = d2; i2 = (unsigned)p; }
          }
        }
      }
    }
  }
  if (lane < NK) ws_knn[(size_t)wq * NK + lane] = (int)keep;
}

// ---------- kernel 4: fused gather + 3-layer MLP + maxpool ----------
// Weights staged per-layer into ONE reused 32KB LDS buffer (broadcast
// ds_read_b128, conflict-free) -- kills the L1 capacity-miss stalls of
// streaming 66.5KB of weights per thread through a 32KB L1.

#define RELU8() { a0=fmaxf(a0,0.f); a1=fmaxf(a1,0.f); a2=fmaxf(a2,0.f); a3=fmaxf(a3,0.f); \
                  a4=fmaxf(a4,0.f); a5=fmaxf(a5,0.f); a6=fmaxf(a6,0.f); a7=fmaxf(a7,0.f); }
#define SCROW(Y, base) { Y[base]=a0; Y[base+1]=a1; Y[base+2]=a2; Y[base+3]=a3; \
                         Y[base+4]=a4; Y[base+5]=a5; Y[base+6]=a6; Y[base+7]=a7; }
#define SCAT8(Y) switch (ob) { \
    case 0: SCROW(Y, 0) break;  case 1: SCROW(Y, 8) break; \
    case 2: SCROW(Y, 16) break; case 3: SCROW(Y, 24) break; \
    case 4: SCROW(Y, 32) break; case 5: SCROW(Y, 40) break; \
    case 6: SCROW(Y, 48) break; case 7: SCROW(Y, 56) break; }
#define BFLY(a) { a = fmaxf(a, __shfl_xor(a, 16, 64)); a = fmaxf(a, __shfl_xor(a, 8, 64)); \
                  a = fmaxf(a, __shfl_xor(a, 4, 64));  a = fmaxf(a, __shfl_xor(a, 2, 64)); \
                  a = fmaxf(a, __shfl_xor(a, 1, 64)); }

// one 4-c chunk of row R accumulated into ACC (float4 LDS broadcast read)
#define ROW4(ACC, R, STRIDE) { \
    float4 w = *(const float4*)(wr + (R) * (STRIDE) + 4 * ch); \
    ACC = fmaf(w.x, x0, ACC); ACC = fmaf(w.y, x1, ACC); \
    ACC = fmaf(w.z, x2, ACC); ACC = fmaf(w.w, x3, ACC); }

#define CHUNK8(XS, STRIDE) { \
    float x0 = XS[4 * ch], x1 = XS[4 * ch + 1], x2 = XS[4 * ch + 2], x3 = XS[4 * ch + 3]; \
    ROW4(a0, 0, STRIDE) ROW4(a1, 1, STRIDE) ROW4(a2, 2, STRIDE) ROW4(a3, 3, STRIDE) \
    ROW4(a4, 4, STRIDE) ROW4(a5, 5, STRIDE) ROW4(a6, 6, STRIDE) ROW4(a7, 7, STRIDE) }

// cooperative stage of N4 float4s from global into LDS
#define STAGE(DST4, SRC4, N4) { \
    for (int t = threadIdx.x; t < (N4); t += 256) \
      ((float4*)(DST4))[t] = ((const float4*)(SRC4))[t]; }

__global__ __launch_bounds__(256) void mlp_kernel(
    const float* __restrict__ featT, const float* __restrict__ loc,
    const float* __restrict__ setloc, const int* __restrict__ ws_knn,
    const float* __restrict__ W1p, const float* __restrict__ b1,
    const float* __restrict__ W2, const float* __restrict__ b2,
    const float* __restrict__ W3, const float* __restrict__ b3,
    float* __restrict__ out) {
  __shared__ __align__(16) float wlds[8192];  // 32KB: max(W1p 4352, W2 4096, W3 8192)
  const int lane = threadIdx.x & 63;
  const int wix = blockIdx.x * 4 + (threadIdx.x >> 6);  // wave id, < 8192
  const int q = wix * 2 + (lane >> 5);                  // query id, < 16384
  const int col = lane & 31;                            // neighbor slot (k)
  const int b = q >> 10, mq = q & 1023;
  const int nk = ws_knn[(size_t)q * NK + col];

  // gather input column: 64 feat channels + 3 rel-loc + zero pad
  const float* fx = featT + ((size_t)(b * NN + nk)) * 64;
  float x[68];
#pragma unroll
  for (int i = 0; i < 16; ++i) {
    float4 v = *(const float4*)(fx + 4 * i);
    x[4 * i] = v.x; x[4 * i + 1] = v.y; x[4 * i + 2] = v.z; x[4 * i + 3] = v.w;
  }
  {
    const float* Lb = loc + (size_t)b * 3 * NN;
    const float* Sb = setloc + (size_t)b * 3 * NM;
    x[64] = Lb[nk] - Sb[mq];
    x[65] = Lb[NN + nk] - Sb[NM + mq];
    x[66] = Lb[2 * NN + nk] - Sb[2 * NM + mq];
    x[67] = 0.0f;  // pairs with W1p zero column
  }

  // ---- layer 1: 68 -> 64 (padded), weights in LDS ----
  STAGE(wlds, W1p, 1088)   // 4352 f32
  __syncthreads();
  float y1[64];
#pragma unroll 1
  for (int ob = 0; ob < 8; ++ob) {
    const float* wr = wlds + ob * 8 * 68;
    const float* bb = b1 + ob * 8;
    float a0 = bb[0], a1 = bb[1], a2 = bb[2], a3 = bb[3];
    float a4 = bb[4], a5 = bb[5], a6 = bb[6], a7 = bb[7];
#pragma unroll
    for (int ch = 0; ch < 17; ++ch) CHUNK8(x, 68)
    RELU8();
    SCAT8(y1);
  }
  __syncthreads();

  // ---- layer 2: 64 -> 64 ----
  STAGE(wlds, W2, 1024)    // 4096 f32
  __syncthreads();
  float y2[64];
#pragma unroll 1
  for (int ob = 0; ob < 8; ++ob) {
    const float* wr = wlds + ob * 8 * 64;
    const float* bb = b2 + ob * 8;
    float a0 = bb[0], a1 = bb[1], a2 = bb[2], a3 = bb[3];
    float a4 = bb[4], a5 = bb[5], a6 = bb[6], a7 = bb[7];
#pragma unroll
    for (int ch = 0; ch < 16; ++ch) CHUNK8(y1, 64)
    RELU8();
    SCAT8(y2);
  }
  __syncthreads();

  // ---- layer 3: 64 -> 128, fused maxpool over the 32 columns + store ----
  STAGE(wlds, W3, 2048)    // 8192 f32
  __syncthreads();
#pragma unroll 1
  for (int ob = 0; ob < 16; ++ob) {
    const float* wr = wlds + ob * 8 * 64;
    const float* bb = b3 + ob * 8;
    float a0 = bb[0], a1 = bb[1], a2 = bb[2], a3 = bb[3];
    float a4 = bb[4], a5 = bb[5], a6 = bb[6], a7 = bb[7];
#pragma unroll
    for (int ch = 0; ch < 16; ++ch) CHUNK8(y2, 64)
    RELU8();
    BFLY(a0); BFLY(a1); BFLY(a2); BFLY(a3);
    BFLY(a4); BFLY(a5); BFLY(a6); BFLY(a7);
    if (col == 0) {
      float* op = out + ((size_t)b * 128 + ob * 8) * NM + mq;
      op[0] = a0;       op[NM] = a1;     op[2 * NM] = a2; op[3 * NM] = a3;
      op[4 * NM] = a4;  op[5 * NM] = a5; op[6 * NM] = a6; op[7 * NM] = a7;
    }
  }
}

// ---------- launch ----------

extern "C" void kernel_launch(void* const* d_in, const int* in_sizes, int n_in,
                              void* d_out, int out_size, void* d_ws, size_t ws_size,
                              hipStream_t stream) {
  (void)in_sizes; (void)n_in; (void)out_size; (void)ws_size;
  const float* feat = (const float*)d_in[0];
  const float* loc  = (const float*)d_in[1];
  const float* W1   = (const float*)d_in[2];
  const float* b1   = (const float*)d_in[3];
  const float* W2   = (const float*)d_in[4];
  const float* b2   = (const float*)d_in[5];
  const float* W3   = (const float*)d_in[6];
  const float* b3   = (const float*)d_in[7];
  float* out = (float*)d_out;

  char* ws = (char*)d_ws;
  int*   ws_knn   = (int*)ws;                           // 16*1024*32 i32 = 2 MB
  float* ws_featT = (float*)(ws + 2097152);             // 16*4096*64 f32 = 16.75 MB
  float* ws_w1p   = (float*)(ws + 2097152 + 16777216);  // 64*68 f32

  float* out_setfeat = out;                          // (16,128,1024)
  float* out_setloc  = out + (size_t)NB * 128 * NM;  // (16,3,1024)

  pad_w1<<<dim3(17), dim3(256), 0, stream>>>(W1, ws_w1p);
  transpose_feat<<<dim3((NB * NN * NC) / 256), dim3(256), 0, stream>>>(feat, ws_featT);
  fps_kernel<<<dim3(NB), dim3(256), 0, stream>>>(loc, out_setloc);
  knn_kernel<<<dim3((NB * NM) / 4), dim3(256), 0, stream>>>(loc, out_setloc, ws_knn);
  mlp_kernel<<<dim3((NB * NM) / 8), dim3(256), 0, stream>>>(
      ws_featT, loc, out_setloc, ws_knn, ws_w1p, b1, W2, b2, W3, b3, out_setfeat);
}